// Round 1
// baseline (325.512 us; speedup 1.0000x reference)
//
#include <hip/hip_runtime.h>
#include <hip/hip_bf16.h>
#include <stdint.h>

typedef __attribute__((ext_vector_type(4))) float f32x4;
typedef __attribute__((ext_vector_type(8))) short s16x8;
typedef uint16_t u16;

#define DEV __device__ __forceinline__

static DEV u16 f2bf(float f) {
  union { float f; uint32_t u; } v; v.f = f;
  uint32_t r = v.u + 0x7fffu + ((v.u >> 16) & 1u);
  return (u16)(r >> 16);
}

#define GLD_LDS16(gp, lp) __builtin_amdgcn_global_load_lds( \
    (const __attribute__((address_space(1))) void*)(gp),    \
    (__attribute__((address_space(3))) void*)(lp), 16, 0, 0)

// ---------------- Kernel 1: LayerNorm + pos_embed -> bf16 ----------------
__global__ __launch_bounds__(256) void k_ln(
    const float* __restrict__ x, const float* __restrict__ pos,
    const float* __restrict__ g, const float* __restrict__ be,
    u16* __restrict__ xp) {
  int row = blockIdx.x;
  size_t base = (size_t)row * 768;
  int t = threadIdx.x;
  float v0 = x[base + t], v1 = x[base + t + 256], v2 = x[base + t + 512];
  float s = v0 + v1 + v2;
  float ss = v0 * v0 + v1 * v1 + v2 * v2;
#pragma unroll
  for (int off = 1; off < 64; off <<= 1) {
    s += __shfl_xor(s, off);
    ss += __shfl_xor(ss, off);
  }
  __shared__ float red[8];
  int wave = t >> 6, lane = t & 63;
  if (lane == 0) { red[wave] = s; red[4 + wave] = ss; }
  __syncthreads();
  float tot = red[0] + red[1] + red[2] + red[3];
  float tss = red[4] + red[5] + red[6] + red[7];
  float mu = tot * (1.0f / 768.0f);
  float var = tss * (1.0f / 768.0f) - mu * mu;
  float rs = rsqrtf(var + 1e-5f);
  float vv[3] = {v0, v1, v2};
#pragma unroll
  for (int i = 0; i < 3; ++i) {
    int c = t + i * 256;
    float val = (vv[i] - mu) * rs * g[c] + be[c] + pos[base + c];
    xp[base + c] = f2bf(val);
  }
}

// ---------------- Kernel 2: transpose + cast f32[K][N] -> bf16[N][K] -----
__global__ __launch_bounds__(256) void k_tr(
    const float* __restrict__ in, u16* __restrict__ out, int K, int N) {
  __shared__ float tile[32][33];
  int n0 = blockIdx.x * 32, k0 = blockIdx.y * 32;
  int tx = threadIdx.x & 31, ty = threadIdx.x >> 5;
#pragma unroll
  for (int r = ty; r < 32; r += 8)
    tile[r][tx] = in[(size_t)(k0 + r) * N + n0 + tx];
  __syncthreads();
#pragma unroll
  for (int r = ty; r < 32; r += 8)
    out[(size_t)(n0 + r) * K + k0 + tx] = f2bf(tile[tx][r]);
}

// ---------------- Kernel 3: QKV GEMM  [8192,768] x [768,2304] ------------
// A row-major bf16, Bt = B^T row-major bf16 [2304][768].
// Epilogue scatters to q/k/v in [B,H,K,D] bf16 (concatenated, 'which' major).
__global__ __launch_bounds__(256) void k_gemm_qkv(
    const u16* __restrict__ A, const u16* __restrict__ Bt,
    const float* __restrict__ bias, u16* __restrict__ qkv) {
  __shared__ u16 Al[128 * 32];
  __shared__ u16 Bl[128 * 32];
  int mt = blockIdx.x, nt = blockIdx.y;
  int t = threadIdx.x, wave = t >> 6, lane = t & 63;
  int lr = lane & 15, lg = lane >> 4;
  f32x4 acc[4][4];
#pragma unroll
  for (int i = 0; i < 4; ++i)
#pragma unroll
    for (int j = 0; j < 4; ++j) acc[i][j] = (f32x4){0.f, 0.f, 0.f, 0.f};
  const size_t Ab = (size_t)mt * 128 * 768;
  const size_t Bb = (size_t)nt * 128 * 768;
  int wr = (wave >> 1) * 64, wc = (wave & 1) * 64;
  for (int kt = 0; kt < 24; ++kt) {
#pragma unroll
    for (int c = 0; c < 2; ++c) {
      int q = c * 256 + wave * 64 + lane;
      int row = q >> 2, kc = q & 3;
      GLD_LDS16(A + Ab + (size_t)row * 768 + kt * 32 + kc * 8,
                &Al[(size_t)(c * 256 + wave * 64) * 8]);
      GLD_LDS16(Bt + Bb + (size_t)row * 768 + kt * 32 + kc * 8,
                &Bl[(size_t)(c * 256 + wave * 64) * 8]);
    }
    __syncthreads();
    s16x8 af[4], bf[4];
#pragma unroll
    for (int mi = 0; mi < 4; ++mi)
      af[mi] = *(const s16x8*)&Al[(wr + mi * 16 + lr) * 32 + lg * 8];
#pragma unroll
    for (int ni = 0; ni < 4; ++ni)
      bf[ni] = *(const s16x8*)&Bl[(wc + ni * 16 + lr) * 32 + lg * 8];
#pragma unroll
    for (int mi = 0; mi < 4; ++mi)
#pragma unroll
      for (int ni = 0; ni < 4; ++ni)
        acc[mi][ni] = __builtin_amdgcn_mfma_f32_16x16x32_bf16(
            af[mi], bf[ni], acc[mi][ni], 0, 0, 0);
    __syncthreads();
  }
#pragma unroll
  for (int ni = 0; ni < 4; ++ni) {
    int col = wc + ni * 16 + lr;
    int n = nt * 128 + col;
    int which = n / 768, cc = n % 768;
    int h = cc >> 6, d = cc & 63;
    float bs = bias[n];
#pragma unroll
    for (int mi = 0; mi < 4; ++mi) {
#pragma unroll
      for (int j = 0; j < 4; ++j) {
        int row = wr + mi * 16 + lg * 4 + j;
        int m = mt * 128 + row;
        int b = m >> 11, kp = m & 2047;
        size_t dst = (size_t)which * (48u * 2048 * 64) +
                     (((size_t)b * 12 + h) * 2048 + kp) * 64 + d;
        qkv[dst] = f2bf(acc[mi][ni][j] + bs);
      }
    }
  }
}

// ---------------- Kernel 4: flash attention ------------------------------
// grid (32 qtiles, 48 bh). Per block: 64 q-rows, iterate 32 kv-tiles of 64.
__global__ __launch_bounds__(256) void k_attn(
    const u16* __restrict__ qkv, const float* __restrict__ bias,
    u16* __restrict__ ctx) {
  __shared__ u16 Kl[64 * 64];
  __shared__ u16 Vt[64 * 64];
  __shared__ u16 Pl[4][16 * 64];
  int qt = blockIdx.x, bh = blockIdx.y;
  int b = bh / 12, h = bh - b * 12;
  int t = threadIdx.x, wave = t >> 6, lane = t & 63;
  int lr = lane & 15, lg = lane >> 4;
  const size_t BHKD = (size_t)48 * 2048 * 64;
  const u16* Q = qkv + (size_t)bh * 2048 * 64;
  const u16* Kg = Q + BHKD;
  const u16* Vg = Q + 2 * BHKD;
  s16x8 qf[2];
  {
    size_t qr = (size_t)(qt * 64 + wave * 16 + lr) * 64;
#pragma unroll
    for (int ki = 0; ki < 2; ++ki)
      qf[ki] = *(const s16x8*)&Q[qr + ki * 32 + lg * 8];
  }
  f32x4 oacc[4];
#pragma unroll
  for (int dt = 0; dt < 4; ++dt) oacc[dt] = (f32x4){0.f, 0.f, 0.f, 0.f};
  float m_run[4], l_run[4];
#pragma unroll
  for (int j = 0; j < 4; ++j) { m_run[j] = -1e30f; l_run[j] = 0.f; }
  const float* bp = bias + ((size_t)b * 2048 + qt * 64 + wave * 16) * 2048;

  for (int kt = 0; kt < 32; ++kt) {
#pragma unroll
    for (int c = 0; c < 2; ++c) {
      int q = c * 256 + wave * 64 + lane;
      int r = q >> 3, dc = q & 7;
      GLD_LDS16(Kg + ((size_t)kt * 64 + r) * 64 + dc * 8,
                &Kl[(size_t)(c * 256 + wave * 64) * 8]);
    }
    {
      int r = t >> 2, dc = t & 3;
      const u16* vp = Vg + ((size_t)kt * 64 + r) * 64 + dc * 16;
      s16x8 v0 = *(const s16x8*)vp;
      s16x8 v1 = *(const s16x8*)(vp + 8);
#pragma unroll
      for (int i = 0; i < 8; ++i) Vt[(dc * 16 + i) * 64 + r] = (u16)v0[i];
#pragma unroll
      for (int i = 0; i < 8; ++i) Vt[(dc * 16 + 8 + i) * 64 + r] = (u16)v1[i];
    }
    __syncthreads();
    f32x4 sa[4];
#pragma unroll
    for (int ct = 0; ct < 4; ++ct) sa[ct] = (f32x4){0.f, 0.f, 0.f, 0.f};
#pragma unroll
    for (int ki = 0; ki < 2; ++ki) {
#pragma unroll
      for (int ct = 0; ct < 4; ++ct) {
        s16x8 kf = *(const s16x8*)&Kl[(ct * 16 + lr) * 64 + ki * 32 + lg * 8];
        sa[ct] = __builtin_amdgcn_mfma_f32_16x16x32_bf16(qf[ki], kf, sa[ct], 0, 0, 0);
      }
    }
    float pv[4][4];
    float rmax[4];
#pragma unroll
    for (int j = 0; j < 4; ++j) rmax[j] = -1e30f;
#pragma unroll
    for (int ct = 0; ct < 4; ++ct) {
      int colg = kt * 64 + ct * 16 + lr;
#pragma unroll
      for (int j = 0; j < 4; ++j) {
        int row = lg * 4 + j;
        float sv = sa[ct][j] * 0.125f + bp[(size_t)row * 2048 + colg];
        pv[j][ct] = sv;
        rmax[j] = fmaxf(rmax[j], sv);
      }
    }
#pragma unroll
    for (int j = 0; j < 4; ++j) {
#pragma unroll
      for (int off = 1; off < 16; off <<= 1)
        rmax[j] = fmaxf(rmax[j], __shfl_xor(rmax[j], off));
    }
    float alpha[4];
#pragma unroll
    for (int j = 0; j < 4; ++j) {
      float mn = fmaxf(m_run[j], rmax[j]);
      alpha[j] = __expf(m_run[j] - mn);
      m_run[j] = mn;
      float rs = 0.f;
#pragma unroll
      for (int ct = 0; ct < 4; ++ct) {
        float p = __expf(pv[j][ct] - mn);
        pv[j][ct] = p;
        rs += p;
      }
#pragma unroll
      for (int off = 1; off < 16; off <<= 1) rs += __shfl_xor(rs, off);
      l_run[j] = l_run[j] * alpha[j] + rs;
    }
#pragma unroll
    for (int ct = 0; ct < 4; ++ct)
#pragma unroll
      for (int j = 0; j < 4; ++j)
        Pl[wave][(lg * 4 + j) * 64 + ct * 16 + lr] = f2bf(pv[j][ct]);
#pragma unroll
    for (int dt = 0; dt < 4; ++dt)
#pragma unroll
      for (int j = 0; j < 4; ++j) oacc[dt][j] *= alpha[j];
#pragma unroll
    for (int ki = 0; ki < 2; ++ki) {
      s16x8 pf = *(const s16x8*)&Pl[wave][lr * 64 + ki * 32 + lg * 8];
#pragma unroll
      for (int dt = 0; dt < 4; ++dt) {
        s16x8 vf = *(const s16x8*)&Vt[(dt * 16 + lr) * 64 + ki * 32 + lg * 8];
        oacc[dt] = __builtin_amdgcn_mfma_f32_16x16x32_bf16(pf, vf, oacc[dt], 0, 0, 0);
      }
    }
    __syncthreads();
  }
#pragma unroll
  for (int j = 0; j < 4; ++j) {
    float inv = 1.0f / l_run[j];
    int qrow = qt * 64 + wave * 16 + lg * 4 + j;
    size_t obase = ((size_t)b * 2048 + qrow) * 768 + h * 64;
#pragma unroll
    for (int dt = 0; dt < 4; ++dt)
      ctx[obase + dt * 16 + lr] = f2bf(oacc[dt][j] * inv);
  }
}

// ---------------- Kernel 5: proj GEMM [8192,768] x [768,768] + b ---------
__global__ __launch_bounds__(256) void k_gemm_proj(
    const u16* __restrict__ A, const u16* __restrict__ Bt,
    const float* __restrict__ bias, float* __restrict__ out) {
  __shared__ u16 Al[128 * 32];
  __shared__ u16 Bl[128 * 32];
  int mt = blockIdx.x, nt = blockIdx.y;
  int t = threadIdx.x, wave = t >> 6, lane = t & 63;
  int lr = lane & 15, lg = lane >> 4;
  f32x4 acc[4][4];
#pragma unroll
  for (int i = 0; i < 4; ++i)
#pragma unroll
    for (int j = 0; j < 4; ++j) acc[i][j] = (f32x4){0.f, 0.f, 0.f, 0.f};
  const size_t Ab = (size_t)mt * 128 * 768;
  const size_t Bb = (size_t)nt * 128 * 768;
  int wr = (wave >> 1) * 64, wc = (wave & 1) * 64;
  for (int kt = 0; kt < 24; ++kt) {
#pragma unroll
    for (int c = 0; c < 2; ++c) {
      int q = c * 256 + wave * 64 + lane;
      int row = q >> 2, kc = q & 3;
      GLD_LDS16(A + Ab + (size_t)row * 768 + kt * 32 + kc * 8,
                &Al[(size_t)(c * 256 + wave * 64) * 8]);
      GLD_LDS16(Bt + Bb + (size_t)row * 768 + kt * 32 + kc * 8,
                &Bl[(size_t)(c * 256 + wave * 64) * 8]);
    }
    __syncthreads();
    s16x8 af[4], bf[4];
#pragma unroll
    for (int mi = 0; mi < 4; ++mi)
      af[mi] = *(const s16x8*)&Al[(wr + mi * 16 + lr) * 32 + lg * 8];
#pragma unroll
    for (int ni = 0; ni < 4; ++ni)
      bf[ni] = *(const s16x8*)&Bl[(wc + ni * 16 + lr) * 32 + lg * 8];
#pragma unroll
    for (int mi = 0; mi < 4; ++mi)
#pragma unroll
      for (int ni = 0; ni < 4; ++ni)
        acc[mi][ni] = __builtin_amdgcn_mfma_f32_16x16x32_bf16(
            af[mi], bf[ni], acc[mi][ni], 0, 0, 0);
    __syncthreads();
  }
#pragma unroll
  for (int ni = 0; ni < 4; ++ni) {
    int col = wc + ni * 16 + lr;
    int n = nt * 128 + col;
    float bs = bias[n];
#pragma unroll
    for (int mi = 0; mi < 4; ++mi) {
#pragma unroll
      for (int j = 0; j < 4; ++j) {
        int row = wr + mi * 16 + lg * 4 + j;
        out[(size_t)(mt * 128 + row) * 768 + n] = acc[mi][ni][j] + bs;
      }
    }
  }
}

extern "C" void kernel_launch(void* const* d_in, const int* in_sizes, int n_in,
                              void* d_out, int out_size, void* d_ws, size_t ws_size,
                              hipStream_t stream) {
  const float* x      = (const float*)d_in[0];
  const float* pos    = (const float*)d_in[1];
  const float* bias   = (const float*)d_in[2];
  const float* ln_g   = (const float*)d_in[3];
  const float* ln_b   = (const float*)d_in[4];
  const float* qkv_w  = (const float*)d_in[5];
  const float* qkv_b  = (const float*)d_in[6];
  const float* proj_w = (const float*)d_in[7];
  const float* proj_b = (const float*)d_in[8];
  float* out = (float*)d_out;

  char* ws = (char*)d_ws;
  u16* xp      = (u16*)ws;              ws += 12582912;   // [8192][768]
  u16* qkv_wt  = (u16*)ws;              ws += 3538944;    // [2304][768]
  u16* proj_wt = (u16*)ws;              ws += 1179648;    // [768][768]
  u16* qkvbuf  = (u16*)ws;              ws += 37748736;   // 3x[B,H,K,D]
  u16* ctx     = (u16*)ws;              ws += 12582912;   // [8192][768]

  k_ln<<<8192, 256, 0, stream>>>(x, pos, ln_g, ln_b, xp);
  k_tr<<<dim3(72, 24), 256, 0, stream>>>(qkv_w, qkv_wt, 768, 2304);
  k_tr<<<dim3(24, 24), 256, 0, stream>>>(proj_w, proj_wt, 768, 768);
  k_gemm_qkv<<<dim3(64, 18), 256, 0, stream>>>(xp, qkv_wt, qkv_b, qkvbuf);
  k_attn<<<dim3(32, 48), 256, 0, stream>>>(qkvbuf, bias, ctx);
  k_gemm_proj<<<dim3(64, 6), 256, 0, stream>>>(ctx, proj_wt, proj_b, out);
}

// Round 2
// 292.598 us; speedup vs baseline: 1.1125x; 1.1125x over previous
//
#include <hip/hip_runtime.h>
#include <hip/hip_bf16.h>
#include <stdint.h>

typedef __attribute__((ext_vector_type(4))) float f32x4;
typedef __attribute__((ext_vector_type(8))) short s16x8;
typedef uint16_t u16;

#define DEV __device__ __forceinline__

static DEV u16 f2bf(float f) {
  union { float f; uint32_t u; } v; v.f = f;
  uint32_t r = v.u + 0x7fffu + ((v.u >> 16) & 1u);
  return (u16)(r >> 16);
}

#define GLD_LDS16(gp, lp) __builtin_amdgcn_global_load_lds( \
    (const __attribute__((address_space(1))) void*)(gp),    \
    (__attribute__((address_space(3))) void*)(lp), 16, 0, 0)

// ---------------- Kernel 1: LayerNorm + pos_embed -> bf16 ----------------
__global__ __launch_bounds__(256) void k_ln(
    const float* __restrict__ x, const float* __restrict__ pos,
    const float* __restrict__ g, const float* __restrict__ be,
    u16* __restrict__ xp) {
  int row = blockIdx.x;
  size_t base = (size_t)row * 768;
  int t = threadIdx.x;
  float v0 = x[base + t], v1 = x[base + t + 256], v2 = x[base + t + 512];
  float s = v0 + v1 + v2;
  float ss = v0 * v0 + v1 * v1 + v2 * v2;
#pragma unroll
  for (int off = 1; off < 64; off <<= 1) {
    s += __shfl_xor(s, off);
    ss += __shfl_xor(ss, off);
  }
  __shared__ float red[8];
  int wave = t >> 6, lane = t & 63;
  if (lane == 0) { red[wave] = s; red[4 + wave] = ss; }
  __syncthreads();
  float tot = red[0] + red[1] + red[2] + red[3];
  float tss = red[4] + red[5] + red[6] + red[7];
  float mu = tot * (1.0f / 768.0f);
  float var = tss * (1.0f / 768.0f) - mu * mu;
  float rs = rsqrtf(var + 1e-5f);
  float vv[3] = {v0, v1, v2};
#pragma unroll
  for (int i = 0; i < 3; ++i) {
    int c = t + i * 256;
    float val = (vv[i] - mu) * rs * g[c] + be[c] + pos[base + c];
    xp[base + c] = f2bf(val);
  }
}

// ---------------- Kernel 2: transpose + cast f32[K][N] -> bf16[N][K] -----
__global__ __launch_bounds__(256) void k_tr(
    const float* __restrict__ in, u16* __restrict__ out, int K, int N) {
  __shared__ float tile[32][33];
  int n0 = blockIdx.x * 32, k0 = blockIdx.y * 32;
  int tx = threadIdx.x & 31, ty = threadIdx.x >> 5;
#pragma unroll
  for (int r = ty; r < 32; r += 8)
    tile[r][tx] = in[(size_t)(k0 + r) * N + n0 + tx];
  __syncthreads();
#pragma unroll
  for (int r = ty; r < 32; r += 8)
    out[(size_t)(n0 + r) * K + k0 + tx] = f2bf(tile[tx][r]);
}

// ---------------- Kernel 2b: transpose V [BH,K,D] -> [BH,D,K] bf16 -------
__global__ __launch_bounds__(256) void k_trv(
    const u16* __restrict__ v, u16* __restrict__ vt) {
  __shared__ u16 tile[64 * 65];
  int kt = blockIdx.x, bh = blockIdx.y;
  int t = threadIdx.x;
  const u16* src = v + ((size_t)bh * 2048 + (size_t)kt * 64) * 64;
#pragma unroll
  for (int it = 0; it < 2; ++it) {
    int q = it * 256 + t;
    int r = q >> 3, c8 = q & 7;  // r = kv row, c8 = d chunk
    s16x8 vv = *(const s16x8*)&src[(size_t)r * 64 + c8 * 8];
#pragma unroll
    for (int i = 0; i < 8; ++i) tile[(c8 * 8 + i) * 65 + r] = (u16)vv[i];
  }
  __syncthreads();
  u16* dst = vt + (size_t)bh * 64 * 2048 + (size_t)kt * 64;
#pragma unroll
  for (int it = 0; it < 2; ++it) {
    int q = it * 256 + t;
    int r = q >> 3, c8 = q & 7;  // r = d row, c8 = kv chunk
    s16x8 ov;
#pragma unroll
    for (int i = 0; i < 8; ++i) ov[i] = tile[r * 65 + c8 * 8 + i];
    *(s16x8*)&dst[(size_t)r * 2048 + c8 * 8] = ov;
  }
}

// ---------------- Kernel 3: QKV GEMM  [8192,768] x [768,2304] ------------
// BK=64, XOR chunk swizzle (chunk ^ (row&7)) on both stage-source and read.
__global__ __launch_bounds__(256) void k_gemm_qkv(
    const u16* __restrict__ A, const u16* __restrict__ Bt,
    const float* __restrict__ bias, u16* __restrict__ qkv) {
  __shared__ u16 Al[128 * 64];
  __shared__ u16 Bl[128 * 64];
  int mt = blockIdx.x, nt = blockIdx.y;
  int t = threadIdx.x, wave = t >> 6, lane = t & 63;
  int lr = lane & 15, lg = lane >> 4;
  f32x4 acc[4][4];
#pragma unroll
  for (int i = 0; i < 4; ++i)
#pragma unroll
    for (int j = 0; j < 4; ++j) acc[i][j] = (f32x4){0.f, 0.f, 0.f, 0.f};
  const size_t Ab = (size_t)mt * 128 * 768;
  const size_t Bb = (size_t)nt * 128 * 768;
  int wr = (wave >> 1) * 64, wc = (wave & 1) * 64;
  for (int kt = 0; kt < 12; ++kt) {
#pragma unroll
    for (int c = 0; c < 4; ++c) {
      int q = c * 256 + t;
      int row = q >> 3, ch = q & 7;
      int sc = ch ^ (row & 7);
      GLD_LDS16(A + Ab + (size_t)row * 768 + kt * 64 + sc * 8,
                &Al[(size_t)(c * 256 + wave * 64) * 8]);
      GLD_LDS16(Bt + Bb + (size_t)row * 768 + kt * 64 + sc * 8,
                &Bl[(size_t)(c * 256 + wave * 64) * 8]);
    }
    __syncthreads();
#pragma unroll
    for (int ki = 0; ki < 2; ++ki) {
      s16x8 af[4], bf[4];
#pragma unroll
      for (int mi = 0; mi < 4; ++mi)
        af[mi] = *(const s16x8*)&Al[(wr + mi * 16 + lr) * 64 +
                                    (((ki * 4 + lg) ^ (lr & 7)) * 8)];
#pragma unroll
      for (int ni = 0; ni < 4; ++ni)
        bf[ni] = *(const s16x8*)&Bl[(wc + ni * 16 + lr) * 64 +
                                    (((ki * 4 + lg) ^ (lr & 7)) * 8)];
#pragma unroll
      for (int mi = 0; mi < 4; ++mi)
#pragma unroll
        for (int ni = 0; ni < 4; ++ni)
          acc[mi][ni] = __builtin_amdgcn_mfma_f32_16x16x32_bf16(
              af[mi], bf[ni], acc[mi][ni], 0, 0, 0);
    }
    __syncthreads();
  }
#pragma unroll
  for (int ni = 0; ni < 4; ++ni) {
    int col = wc + ni * 16 + lr;
    int n = nt * 128 + col;
    int which = n / 768, cc = n % 768;
    int h = cc >> 6, d = cc & 63;
    float bs = bias[n];
#pragma unroll
    for (int mi = 0; mi < 4; ++mi) {
#pragma unroll
      for (int j = 0; j < 4; ++j) {
        int row = wr + mi * 16 + lg * 4 + j;
        int m = mt * 128 + row;
        int b = m >> 11, kp = m & 2047;
        size_t dst = (size_t)which * (48u * 2048 * 64) +
                     (((size_t)b * 12 + h) * 2048 + kp) * 64 + d;
        qkv[dst] = f2bf(acc[mi][ni][j] + bs);
      }
    }
  }
}

// ---------------- Kernel 4: flash attention ------------------------------
// 64 q-rows/block, 32 kv-tiles of 64. K, V^T, bias staged via
// global_load_lds with source pre-swizzle; all LDS reads XOR-swizzled.
__global__ __launch_bounds__(256) void k_attn(
    const u16* __restrict__ qkv, const u16* __restrict__ vtg,
    const float* __restrict__ bias, u16* __restrict__ ctx) {
  __shared__ u16 Kl[64 * 64];
  __shared__ u16 Vtl[64 * 64];
  __shared__ u16 Pl[4][16 * 64];
  __shared__ float Bs[64 * 64];
  int qt = blockIdx.x, bh = blockIdx.y;
  int b = bh / 12, h = bh - b * 12;
  int t = threadIdx.x, wave = t >> 6, lane = t & 63;
  int lr = lane & 15, lg = lane >> 4;
  const size_t BHKD = (size_t)48 * 2048 * 64;
  const u16* Q = qkv + (size_t)bh * 2048 * 64;
  const u16* Kg = Q + BHKD;
  const u16* Vt = vtg + (size_t)bh * 64 * 2048;
  const float* Bg = bias + ((size_t)b * 2048 + qt * 64) * 2048;
  s16x8 qf[2];
  {
    size_t qr = (size_t)(qt * 64 + wave * 16 + lr) * 64;
#pragma unroll
    for (int ki = 0; ki < 2; ++ki)
      qf[ki] = *(const s16x8*)&Q[qr + ki * 32 + lg * 8];
  }
  f32x4 oacc[4];
#pragma unroll
  for (int dt = 0; dt < 4; ++dt) oacc[dt] = (f32x4){0.f, 0.f, 0.f, 0.f};
  float m_run[4], l_run[4];
#pragma unroll
  for (int j = 0; j < 4; ++j) { m_run[j] = -1e30f; l_run[j] = 0.f; }

  for (int kt = 0; kt < 32; ++kt) {
#pragma unroll
    for (int c = 0; c < 2; ++c) {
      int q = c * 256 + t;
      int r = q >> 3, ch = q & 7;
      int sc = ch ^ (r & 7);
      GLD_LDS16(Kg + ((size_t)(kt * 64 + r)) * 64 + sc * 8,
                &Kl[(size_t)(c * 256 + wave * 64) * 8]);
      GLD_LDS16(Vt + (size_t)r * 2048 + kt * 64 + sc * 8,
                &Vtl[(size_t)(c * 256 + wave * 64) * 8]);
    }
#pragma unroll
    for (int c = 0; c < 4; ++c) {
      int q = c * 256 + t;
      int r = q >> 4, ch = q & 15;
      int sc = ch ^ (r & 15);
      GLD_LDS16(Bg + (size_t)r * 2048 + kt * 64 + sc * 4,
                &Bs[(size_t)(c * 256 + wave * 64) * 4]);
    }
    __syncthreads();
    f32x4 sa[4];
#pragma unroll
    for (int ct = 0; ct < 4; ++ct) sa[ct] = (f32x4){0.f, 0.f, 0.f, 0.f};
#pragma unroll
    for (int ki = 0; ki < 2; ++ki) {
#pragma unroll
      for (int ct = 0; ct < 4; ++ct) {
        int row = ct * 16 + lr;
        s16x8 kf = *(const s16x8*)&Kl[row * 64 +
                                      (((ki * 4 + lg) ^ (lr & 7)) * 8)];
        sa[ct] = __builtin_amdgcn_mfma_f32_16x16x32_bf16(qf[ki], kf, sa[ct], 0, 0, 0);
      }
    }
    float pv[4][4];
    float rmax[4];
#pragma unroll
    for (int j = 0; j < 4; ++j) rmax[j] = -1e30f;
#pragma unroll
    for (int ct = 0; ct < 4; ++ct) {
      int col = ct * 16 + lr;
#pragma unroll
      for (int j = 0; j < 4; ++j) {
        int s = lg * 4 + j;
        float bval = Bs[(wave * 16 + s) * 64 + (col ^ (s << 2))];
        float sv = sa[ct][j] * 0.125f + bval;
        pv[j][ct] = sv;
        rmax[j] = fmaxf(rmax[j], sv);
      }
    }
#pragma unroll
    for (int j = 0; j < 4; ++j) {
#pragma unroll
      for (int off = 1; off < 16; off <<= 1)
        rmax[j] = fmaxf(rmax[j], __shfl_xor(rmax[j], off));
    }
    float alpha[4];
#pragma unroll
    for (int j = 0; j < 4; ++j) {
      float mn = fmaxf(m_run[j], rmax[j]);
      alpha[j] = __expf(m_run[j] - mn);
      m_run[j] = mn;
      float rs = 0.f;
#pragma unroll
      for (int ct = 0; ct < 4; ++ct) {
        float p = __expf(pv[j][ct] - mn);
        pv[j][ct] = p;
        rs += p;
      }
#pragma unroll
      for (int off = 1; off < 16; off <<= 1) rs += __shfl_xor(rs, off);
      l_run[j] = l_run[j] * alpha[j] + rs;
    }
#pragma unroll
    for (int ct = 0; ct < 4; ++ct) {
#pragma unroll
      for (int j = 0; j < 4; ++j) {
        int rw = lg * 4 + j;
        int col = ct * 16 + lr;
        Pl[wave][rw * 64 + (col ^ ((rw & 7) << 3))] = f2bf(pv[j][ct]);
      }
    }
#pragma unroll
    for (int dt = 0; dt < 4; ++dt)
#pragma unroll
      for (int j = 0; j < 4; ++j) oacc[dt][j] *= alpha[j];
#pragma unroll
    for (int ki = 0; ki < 2; ++ki) {
      s16x8 pf = *(const s16x8*)&Pl[wave][lr * 64 +
                                          ((ki * 32 + lg * 8) ^ ((lr & 7) << 3))];
#pragma unroll
      for (int dt = 0; dt < 4; ++dt) {
        int rowd = dt * 16 + lr;
        s16x8 vf = *(const s16x8*)&Vtl[rowd * 64 +
                                       (((ki * 4 + lg) ^ (lr & 7)) * 8)];
        oacc[dt] = __builtin_amdgcn_mfma_f32_16x16x32_bf16(pf, vf, oacc[dt], 0, 0, 0);
      }
    }
    __syncthreads();
  }
#pragma unroll
  for (int j = 0; j < 4; ++j) {
    float inv = 1.0f / l_run[j];
    int qrow = qt * 64 + wave * 16 + lg * 4 + j;
    size_t obase = ((size_t)b * 2048 + qrow) * 768 + h * 64;
#pragma unroll
    for (int dt = 0; dt < 4; ++dt)
      ctx[obase + dt * 16 + lr] = f2bf(oacc[dt][j] * inv);
  }
}

// ---------------- Kernel 5: proj GEMM [8192,768] x [768,768] + b ---------
__global__ __launch_bounds__(256) void k_gemm_proj(
    const u16* __restrict__ A, const u16* __restrict__ Bt,
    const float* __restrict__ bias, float* __restrict__ out) {
  __shared__ u16 Al[128 * 64];
  __shared__ u16 Bl[128 * 64];
  int mt = blockIdx.x, nt = blockIdx.y;
  int t = threadIdx.x, wave = t >> 6, lane = t & 63;
  int lr = lane & 15, lg = lane >> 4;
  f32x4 acc[4][4];
#pragma unroll
  for (int i = 0; i < 4; ++i)
#pragma unroll
    for (int j = 0; j < 4; ++j) acc[i][j] = (f32x4){0.f, 0.f, 0.f, 0.f};
  const size_t Ab = (size_t)mt * 128 * 768;
  const size_t Bb = (size_t)nt * 128 * 768;
  int wr = (wave >> 1) * 64, wc = (wave & 1) * 64;
  for (int kt = 0; kt < 12; ++kt) {
#pragma unroll
    for (int c = 0; c < 4; ++c) {
      int q = c * 256 + t;
      int row = q >> 3, ch = q & 7;
      int sc = ch ^ (row & 7);
      GLD_LDS16(A + Ab + (size_t)row * 768 + kt * 64 + sc * 8,
                &Al[(size_t)(c * 256 + wave * 64) * 8]);
      GLD_LDS16(Bt + Bb + (size_t)row * 768 + kt * 64 + sc * 8,
                &Bl[(size_t)(c * 256 + wave * 64) * 8]);
    }
    __syncthreads();
#pragma unroll
    for (int ki = 0; ki < 2; ++ki) {
      s16x8 af[4], bf[4];
#pragma unroll
      for (int mi = 0; mi < 4; ++mi)
        af[mi] = *(const s16x8*)&Al[(wr + mi * 16 + lr) * 64 +
                                    (((ki * 4 + lg) ^ (lr & 7)) * 8)];
#pragma unroll
      for (int ni = 0; ni < 4; ++ni)
        bf[ni] = *(const s16x8*)&Bl[(wc + ni * 16 + lr) * 64 +
                                    (((ki * 4 + lg) ^ (lr & 7)) * 8)];
#pragma unroll
      for (int mi = 0; mi < 4; ++mi)
#pragma unroll
        for (int ni = 0; ni < 4; ++ni)
          acc[mi][ni] = __builtin_amdgcn_mfma_f32_16x16x32_bf16(
              af[mi], bf[ni], acc[mi][ni], 0, 0, 0);
    }
    __syncthreads();
  }
#pragma unroll
  for (int ni = 0; ni < 4; ++ni) {
    int col = wc + ni * 16 + lr;
    int n = nt * 128 + col;
    float bs = bias[n];
#pragma unroll
    for (int mi = 0; mi < 4; ++mi) {
#pragma unroll
      for (int j = 0; j < 4; ++j) {
        int row = wr + mi * 16 + lg * 4 + j;
        out[(size_t)(mt * 128 + row) * 768 + n] = acc[mi][ni][j] + bs;
      }
    }
  }
}

extern "C" void kernel_launch(void* const* d_in, const int* in_sizes, int n_in,
                              void* d_out, int out_size, void* d_ws, size_t ws_size,
                              hipStream_t stream) {
  const float* x      = (const float*)d_in[0];
  const float* pos    = (const float*)d_in[1];
  const float* bias   = (const float*)d_in[2];
  const float* ln_g   = (const float*)d_in[3];
  const float* ln_b   = (const float*)d_in[4];
  const float* qkv_w  = (const float*)d_in[5];
  const float* qkv_b  = (const float*)d_in[6];
  const float* proj_w = (const float*)d_in[7];
  const float* proj_b = (const float*)d_in[8];
  float* out = (float*)d_out;

  char* ws = (char*)d_ws;
  u16* xp      = (u16*)ws;              ws += 12582912;   // [8192][768]
  u16* qkv_wt  = (u16*)ws;              ws += 3538944;    // [2304][768]
  u16* proj_wt = (u16*)ws;              ws += 1179648;    // [768][768]
  u16* qkvbuf  = (u16*)ws;              ws += 37748736;   // 3x[B,H,K,D]
  u16* ctx     = (u16*)ws;              ws += 12582912;   // [8192][768]
  u16* vtg     = (u16*)ws;              ws += 12582912;   // [B,H,D,K]

  k_ln<<<8192, 256, 0, stream>>>(x, pos, ln_g, ln_b, xp);
  k_tr<<<dim3(72, 24), 256, 0, stream>>>(qkv_w, qkv_wt, 768, 2304);
  k_tr<<<dim3(24, 24), 256, 0, stream>>>(proj_w, proj_wt, 768, 768);
  k_gemm_qkv<<<dim3(64, 18), 256, 0, stream>>>(xp, qkv_wt, qkv_b, qkvbuf);
  k_trv<<<dim3(32, 48), 256, 0, stream>>>(qkvbuf + 2 * (size_t)48 * 2048 * 64, vtg);
  k_attn<<<dim3(32, 48), 256, 0, stream>>>(qkvbuf, vtg, bias, ctx);
  k_gemm_proj<<<dim3(64, 6), 256, 0, stream>>>(ctx, proj_wt, proj_b, out);
}

// Round 3
// 230.184 us; speedup vs baseline: 1.4141x; 1.2711x over previous
//
#include <hip/hip_runtime.h>
#include <hip/hip_bf16.h>
#include <stdint.h>

typedef __attribute__((ext_vector_type(4))) float f32x4;
typedef __attribute__((ext_vector_type(8))) short s16x8;
typedef __attribute__((ext_vector_type(4))) short s16x4;
typedef uint16_t u16;

#define DEV __device__ __forceinline__

static DEV u16 f2bf(float f) {
  union { float f; uint32_t u; } v; v.f = f;
  uint32_t r = v.u + 0x7fffu + ((v.u >> 16) & 1u);
  return (u16)(r >> 16);
}

static DEV uint32_t cvt_pk_bf16(float lo, float hi) {
  uint32_t r;
  asm("v_cvt_pk_bf16_f32 %0, %1, %2" : "=v"(r) : "v"(lo), "v"(hi));
  return r;
}

#define GLD_LDS16(gp, lp) __builtin_amdgcn_global_load_lds( \
    (const __attribute__((address_space(1))) void*)(gp),    \
    (__attribute__((address_space(3))) void*)(lp), 16, 0, 0)

// ---------------- Kernel 1: LayerNorm + pos_embed -> bf16 ----------------
__global__ __launch_bounds__(256) void k_ln(
    const float* __restrict__ x, const float* __restrict__ pos,
    const float* __restrict__ g, const float* __restrict__ be,
    u16* __restrict__ xp) {
  int row = blockIdx.x;
  size_t base = (size_t)row * 768;
  int t = threadIdx.x;
  float v0 = x[base + t], v1 = x[base + t + 256], v2 = x[base + t + 512];
  float s = v0 + v1 + v2;
  float ss = v0 * v0 + v1 * v1 + v2 * v2;
#pragma unroll
  for (int off = 1; off < 64; off <<= 1) {
    s += __shfl_xor(s, off);
    ss += __shfl_xor(ss, off);
  }
  __shared__ float red[8];
  int wave = t >> 6, lane = t & 63;
  if (lane == 0) { red[wave] = s; red[4 + wave] = ss; }
  __syncthreads();
  float tot = red[0] + red[1] + red[2] + red[3];
  float tss = red[4] + red[5] + red[6] + red[7];
  float mu = tot * (1.0f / 768.0f);
  float var = tss * (1.0f / 768.0f) - mu * mu;
  float rs = rsqrtf(var + 1e-5f);
  float vv[3] = {v0, v1, v2};
#pragma unroll
  for (int i = 0; i < 3; ++i) {
    int c = t + i * 256;
    float val = (vv[i] - mu) * rs * g[c] + be[c] + pos[base + c];
    xp[base + c] = f2bf(val);
  }
}

// ---------------- Kernel 2: transpose + cast f32[K][N] -> bf16[N][K] -----
__global__ __launch_bounds__(256) void k_tr(
    const float* __restrict__ in, u16* __restrict__ out, int K, int N) {
  __shared__ float tile[32][33];
  int n0 = blockIdx.x * 32, k0 = blockIdx.y * 32;
  int tx = threadIdx.x & 31, ty = threadIdx.x >> 5;
#pragma unroll
  for (int r = ty; r < 32; r += 8)
    tile[r][tx] = in[(size_t)(k0 + r) * N + n0 + tx];
  __syncthreads();
#pragma unroll
  for (int r = ty; r < 32; r += 8)
    out[(size_t)(n0 + r) * K + k0 + tx] = f2bf(tile[tx][r]);
}

// ---------------- Kernel 2b: transpose V [BH,K,D] -> [BH,D,K] bf16 -------
__global__ __launch_bounds__(256) void k_trv(
    const u16* __restrict__ v, u16* __restrict__ vt) {
  __shared__ u16 tile[64 * 65];
  int kt = blockIdx.x, bh = blockIdx.y;
  int t = threadIdx.x;
  const u16* src = v + ((size_t)bh * 2048 + (size_t)kt * 64) * 64;
#pragma unroll
  for (int it = 0; it < 2; ++it) {
    int q = it * 256 + t;
    int r = q >> 3, c8 = q & 7;
    s16x8 vv = *(const s16x8*)&src[(size_t)r * 64 + c8 * 8];
#pragma unroll
    for (int i = 0; i < 8; ++i) tile[(c8 * 8 + i) * 65 + r] = (u16)vv[i];
  }
  __syncthreads();
  u16* dst = vt + (size_t)bh * 64 * 2048 + (size_t)kt * 64;
#pragma unroll
  for (int it = 0; it < 2; ++it) {
    int q = it * 256 + t;
    int r = q >> 3, c8 = q & 7;
    s16x8 ov;
#pragma unroll
    for (int i = 0; i < 8; ++i) ov[i] = tile[r * 65 + c8 * 8 + i];
    *(s16x8*)&dst[(size_t)r * 2048 + c8 * 8] = ov;
  }
}

// ---------------- Kernel 3: QKV GEMM  [8192,768] x [768,2304] ------------
__global__ __launch_bounds__(256) void k_gemm_qkv(
    const u16* __restrict__ A, const u16* __restrict__ Bt,
    const float* __restrict__ bias, u16* __restrict__ qkv) {
  __shared__ u16 Al[128 * 64];
  __shared__ u16 Bl[128 * 64];
  int mt = blockIdx.x, nt = blockIdx.y;
  int t = threadIdx.x, wave = t >> 6, lane = t & 63;
  int lr = lane & 15, lg = lane >> 4;
  f32x4 acc[4][4];
#pragma unroll
  for (int i = 0; i < 4; ++i)
#pragma unroll
    for (int j = 0; j < 4; ++j) acc[i][j] = (f32x4){0.f, 0.f, 0.f, 0.f};
  const size_t Ab = (size_t)mt * 128 * 768;
  const size_t Bb = (size_t)nt * 128 * 768;
  int wr = (wave >> 1) * 64, wc = (wave & 1) * 64;
  for (int kt = 0; kt < 12; ++kt) {
#pragma unroll
    for (int c = 0; c < 4; ++c) {
      int q = c * 256 + t;
      int row = q >> 3, ch = q & 7;
      int sc = ch ^ (row & 7);
      GLD_LDS16(A + Ab + (size_t)row * 768 + kt * 64 + sc * 8,
                &Al[(size_t)(c * 256 + wave * 64) * 8]);
      GLD_LDS16(Bt + Bb + (size_t)row * 768 + kt * 64 + sc * 8,
                &Bl[(size_t)(c * 256 + wave * 64) * 8]);
    }
    __syncthreads();
#pragma unroll
    for (int ki = 0; ki < 2; ++ki) {
      s16x8 af[4], bf[4];
#pragma unroll
      for (int mi = 0; mi < 4; ++mi)
        af[mi] = *(const s16x8*)&Al[(wr + mi * 16 + lr) * 64 +
                                    (((ki * 4 + lg) ^ (lr & 7)) * 8)];
#pragma unroll
      for (int ni = 0; ni < 4; ++ni)
        bf[ni] = *(const s16x8*)&Bl[(wc + ni * 16 + lr) * 64 +
                                    (((ki * 4 + lg) ^ (lr & 7)) * 8)];
#pragma unroll
      for (int mi = 0; mi < 4; ++mi)
#pragma unroll
        for (int ni = 0; ni < 4; ++ni)
          acc[mi][ni] = __builtin_amdgcn_mfma_f32_16x16x32_bf16(
              af[mi], bf[ni], acc[mi][ni], 0, 0, 0);
    }
    __syncthreads();
  }
#pragma unroll
  for (int ni = 0; ni < 4; ++ni) {
    int col = wc + ni * 16 + lr;
    int n = nt * 128 + col;
    int which = n / 768, cc = n % 768;
    int h = cc >> 6, d = cc & 63;
    float bs = bias[n];
#pragma unroll
    for (int mi = 0; mi < 4; ++mi) {
#pragma unroll
      for (int j = 0; j < 4; ++j) {
        int row = wr + mi * 16 + lg * 4 + j;
        int m = mt * 128 + row;
        int b = m >> 11, kp = m & 2047;
        size_t dst = (size_t)which * (48u * 2048 * 64) +
                     (((size_t)b * 12 + h) * 2048 + kp) * 64 + d;
        qkv[dst] = f2bf(acc[mi][ni][j] + bs);
      }
    }
  }
}

// ---------------- Kernel 4: flash attention (swapped-QK, reg softmax) ----
// 1-D grid 1536 blocks; XCD-bijective swizzle with head innermost so the 12
// head-blocks sharing one bias panel co-reside on one XCD (bias L2 reuse).
// Per tile: lane (lr,lg) holds S[q=lr][kv=ct*16+lg*4+j] after mfma(K,Q);
// softmax is per-lane + 2 shfl; P redistributed via 16 bpermute -> PV as
// mfma(Vt, P) giving O^T[d][q=lr] so alpha rescale is per-lane scalar.
__global__ __launch_bounds__(256) void k_attn(
    const u16* __restrict__ qkv, const u16* __restrict__ vtg,
    const float* __restrict__ bias, u16* __restrict__ ctx) {
  __shared__ u16 Kl[64 * 64];
  __shared__ u16 Vtl[64 * 64];
  __shared__ float Bs[64 * 64];
  int bid = blockIdx.x;
  int swz = (bid & 7) * 192 + (bid >> 3);   // 1536 = 8*192, bijective
  int h = swz % 12;
  int bq = swz / 12;        // 0..127
  int qt = bq & 31;
  int b = bq >> 5;
  int bh = b * 12 + h;
  int t = threadIdx.x, wave = t >> 6, lane = t & 63;
  int lr = lane & 15, lg = lane >> 4;
  const size_t BHKD = (size_t)48 * 2048 * 64;
  const u16* Q = qkv + (size_t)bh * 2048 * 64;
  const u16* Kg = Q + BHKD;
  const u16* Vt = vtg + (size_t)bh * 64 * 2048;
  const float* Bg = bias + ((size_t)b * 2048 + qt * 64) * 2048;
  s16x8 qf[2];
  {
    size_t qr = (size_t)(qt * 64 + wave * 16 + lr) * 64;
#pragma unroll
    for (int ki = 0; ki < 2; ++ki)
      qf[ki] = *(const s16x8*)&Q[qr + ki * 32 + lg * 8];
  }
  f32x4 oacc[4];
#pragma unroll
  for (int dt = 0; dt < 4; ++dt) oacc[dt] = (f32x4){0.f, 0.f, 0.f, 0.f};
  float m_run = -1e30f, l_run = 0.f;
  int srcA = ((lane & 16) << 1) | lr;   // lane of lg'=(lg&1)*2, same lr
  int srcB = srcA + 16;
  bool hi = (lane & 32) != 0;           // lg>>1

  for (int kt = 0; kt < 32; ++kt) {
#pragma unroll
    for (int c = 0; c < 2; ++c) {
      int q = c * 256 + t;
      int r = q >> 3, ch = q & 7;
      int sc = ch ^ (r & 7);
      GLD_LDS16(Kg + ((size_t)(kt * 64 + r)) * 64 + sc * 8,
                &Kl[(size_t)(c * 256 + wave * 64) * 8]);
      GLD_LDS16(Vt + (size_t)r * 2048 + kt * 64 + sc * 8,
                &Vtl[(size_t)(c * 256 + wave * 64) * 8]);
    }
#pragma unroll
    for (int c = 0; c < 4; ++c) {
      int q = c * 256 + t;
      int r = q >> 4, ch = q & 15;
      int sc = ch ^ (r & 15);
      GLD_LDS16(Bg + (size_t)r * 2048 + kt * 64 + sc * 4,
                &Bs[(size_t)(c * 256 + wave * 64) * 4]);
    }
    __syncthreads();
    // QK^T swapped: sa[ct][j] = S[q=lr][kv=ct*16+lg*4+j]
    f32x4 sa[4];
#pragma unroll
    for (int ct = 0; ct < 4; ++ct) sa[ct] = (f32x4){0.f, 0.f, 0.f, 0.f};
#pragma unroll
    for (int ki = 0; ki < 2; ++ki) {
#pragma unroll
      for (int ct = 0; ct < 4; ++ct) {
        s16x8 kf = *(const s16x8*)&Kl[(ct * 16 + lr) * 64 +
                                      (((ki * 4 + lg) ^ (lr & 7)) * 8)];
        sa[ct] = __builtin_amdgcn_mfma_f32_16x16x32_bf16(kf, qf[ki], sa[ct], 0, 0, 0);
      }
    }
    // bias + scale, per-lane row q = wave*16+lr
    float p[16];
    float rmax = -1e30f;
#pragma unroll
    for (int ct = 0; ct < 4; ++ct) {
      f32x4 bv = *(const f32x4*)&Bs[(wave * 16 + lr) * 64 +
                                    (((ct * 4 + lg) ^ lr) * 4)];
#pragma unroll
      for (int j = 0; j < 4; ++j) {
        float sv = sa[ct][j] * 0.125f + bv[j];
        p[ct * 4 + j] = sv;
        rmax = fmaxf(rmax, sv);
      }
    }
    rmax = fmaxf(rmax, __shfl_xor(rmax, 16));
    rmax = fmaxf(rmax, __shfl_xor(rmax, 32));
    float mn = fmaxf(m_run, rmax);
    float alpha = __expf(m_run - mn);
    m_run = mn;
    float rs = 0.f;
#pragma unroll
    for (int i = 0; i < 16; ++i) {
      p[i] = __expf(p[i] - mn);
      rs += p[i];
    }
    rs += __shfl_xor(rs, 16);
    rs += __shfl_xor(rs, 32);
    l_run = l_run * alpha + rs;
    // pack P -> bf16 pairs: pk[ct][w] = (p[ct*4+2w], p[ct*4+2w+1])
    uint32_t pk[4][2];
#pragma unroll
    for (int ct = 0; ct < 4; ++ct)
#pragma unroll
      for (int w = 0; w < 2; ++w)
        pk[ct][w] = cvt_pk_bf16(p[ct * 4 + 2 * w], p[ct * 4 + 2 * w + 1]);
    // redistribute: paf[ki] elem i = P[q=lr][kv=ki*32+lg*8+i]
    s16x8 paf[2];
#pragma unroll
    for (int ki = 0; ki < 2; ++ki) {
      uint32_t a0 = __shfl((int)pk[2 * ki][0], srcA);
      uint32_t b0 = __shfl((int)pk[2 * ki + 1][0], srcA);
      uint32_t a1 = __shfl((int)pk[2 * ki][1], srcA);
      uint32_t b1 = __shfl((int)pk[2 * ki + 1][1], srcA);
      uint32_t a2 = __shfl((int)pk[2 * ki][0], srcB);
      uint32_t b2 = __shfl((int)pk[2 * ki + 1][0], srcB);
      uint32_t a3 = __shfl((int)pk[2 * ki][1], srcB);
      uint32_t b3 = __shfl((int)pk[2 * ki + 1][1], srcB);
      union { uint32_t u[4]; s16x8 v; } pu;
      pu.u[0] = hi ? b0 : a0;
      pu.u[1] = hi ? b1 : a1;
      pu.u[2] = hi ? b2 : a2;
      pu.u[3] = hi ? b3 : a3;
      paf[ki] = pu.v;
    }
    // rescale O by alpha (per-lane scalar)
#pragma unroll
    for (int dt = 0; dt < 4; ++dt)
#pragma unroll
      for (int j = 0; j < 4; ++j) oacc[dt][j] *= alpha;
    // PV: O^T[d][q=lr]; A = Vt rows (d), B = P rows (q)
#pragma unroll
    for (int ki = 0; ki < 2; ++ki) {
#pragma unroll
      for (int dt = 0; dt < 4; ++dt) {
        s16x8 vf = *(const s16x8*)&Vtl[(dt * 16 + lr) * 64 +
                                       (((ki * 4 + lg) ^ (lr & 7)) * 8)];
        oacc[dt] = __builtin_amdgcn_mfma_f32_16x16x32_bf16(vf, paf[ki], oacc[dt], 0, 0, 0);
      }
    }
    __syncthreads();
  }
  float inv = 1.0f / l_run;
  int qrow = qt * 64 + wave * 16 + lr;
  size_t obase = ((size_t)b * 2048 + qrow) * 768 + h * 64;
#pragma unroll
  for (int dt = 0; dt < 4; ++dt) {
    s16x4 o4;
#pragma unroll
    for (int j = 0; j < 4; ++j) o4[j] = (short)f2bf(oacc[dt][j] * inv);
    *(s16x4*)&ctx[obase + dt * 16 + lg * 4] = o4;
  }
}

// ---------------- Kernel 5: proj GEMM [8192,768] x [768,768] + b ---------
__global__ __launch_bounds__(256) void k_gemm_proj(
    const u16* __restrict__ A, const u16* __restrict__ Bt,
    const float* __restrict__ bias, float* __restrict__ out) {
  __shared__ u16 Al[128 * 64];
  __shared__ u16 Bl[128 * 64];
  int mt = blockIdx.x, nt = blockIdx.y;
  int t = threadIdx.x, wave = t >> 6, lane = t & 63;
  int lr = lane & 15, lg = lane >> 4;
  f32x4 acc[4][4];
#pragma unroll
  for (int i = 0; i < 4; ++i)
#pragma unroll
    for (int j = 0; j < 4; ++j) acc[i][j] = (f32x4){0.f, 0.f, 0.f, 0.f};
  const size_t Ab = (size_t)mt * 128 * 768;
  const size_t Bb = (size_t)nt * 128 * 768;
  int wr = (wave >> 1) * 64, wc = (wave & 1) * 64;
  for (int kt = 0; kt < 12; ++kt) {
#pragma unroll
    for (int c = 0; c < 4; ++c) {
      int q = c * 256 + t;
      int row = q >> 3, ch = q & 7;
      int sc = ch ^ (row & 7);
      GLD_LDS16(A + Ab + (size_t)row * 768 + kt * 64 + sc * 8,
                &Al[(size_t)(c * 256 + wave * 64) * 8]);
      GLD_LDS16(Bt + Bb + (size_t)row * 768 + kt * 64 + sc * 8,
                &Bl[(size_t)(c * 256 + wave * 64) * 8]);
    }
    __syncthreads();
#pragma unroll
    for (int ki = 0; ki < 2; ++ki) {
      s16x8 af[4], bf[4];
#pragma unroll
      for (int mi = 0; mi < 4; ++mi)
        af[mi] = *(const s16x8*)&Al[(wr + mi * 16 + lr) * 64 +
                                    (((ki * 4 + lg) ^ (lr & 7)) * 8)];
#pragma unroll
      for (int ni = 0; ni < 4; ++ni)
        bf[ni] = *(const s16x8*)&Bl[(wc + ni * 16 + lr) * 64 +
                                    (((ki * 4 + lg) ^ (lr & 7)) * 8)];
#pragma unroll
      for (int mi = 0; mi < 4; ++mi)
#pragma unroll
        for (int ni = 0; ni < 4; ++ni)
          acc[mi][ni] = __builtin_amdgcn_mfma_f32_16x16x32_bf16(
              af[mi], bf[ni], acc[mi][ni], 0, 0, 0);
    }
    __syncthreads();
  }
#pragma unroll
  for (int ni = 0; ni < 4; ++ni) {
    int col = wc + ni * 16 + lr;
    int n = nt * 128 + col;
    float bs = bias[n];
#pragma unroll
    for (int mi = 0; mi < 4; ++mi) {
#pragma unroll
      for (int j = 0; j < 4; ++j) {
        int row = wr + mi * 16 + lg * 4 + j;
        out[(size_t)(mt * 128 + row) * 768 + n] = acc[mi][ni][j] + bs;
      }
    }
  }
}

extern "C" void kernel_launch(void* const* d_in, const int* in_sizes, int n_in,
                              void* d_out, int out_size, void* d_ws, size_t ws_size,
                              hipStream_t stream) {
  const float* x      = (const float*)d_in[0];
  const float* pos    = (const float*)d_in[1];
  const float* bias   = (const float*)d_in[2];
  const float* ln_g   = (const float*)d_in[3];
  const float* ln_b   = (const float*)d_in[4];
  const float* qkv_w  = (const float*)d_in[5];
  const float* qkv_b  = (const float*)d_in[6];
  const float* proj_w = (const float*)d_in[7];
  const float* proj_b = (const float*)d_in[8];
  float* out = (float*)d_out;

  char* ws = (char*)d_ws;
  u16* xp      = (u16*)ws;              ws += 12582912;   // [8192][768]
  u16* qkv_wt  = (u16*)ws;              ws += 3538944;    // [2304][768]
  u16* proj_wt = (u16*)ws;              ws += 1179648;    // [768][768]
  u16* qkvbuf  = (u16*)ws;              ws += 37748736;   // 3x[B,H,K,D]
  u16* ctx     = (u16*)ws;              ws += 12582912;   // [8192][768]
  u16* vtg     = (u16*)ws;              ws += 12582912;   // [B,H,D,K]

  k_ln<<<8192, 256, 0, stream>>>(x, pos, ln_g, ln_b, xp);
  k_tr<<<dim3(72, 24), 256, 0, stream>>>(qkv_w, qkv_wt, 768, 2304);
  k_tr<<<dim3(24, 24), 256, 0, stream>>>(proj_w, proj_wt, 768, 768);
  k_gemm_qkv<<<dim3(64, 18), 256, 0, stream>>>(xp, qkv_wt, qkv_b, qkvbuf);
  k_trv<<<dim3(32, 48), 256, 0, stream>>>(qkvbuf + 2 * (size_t)48 * 2048 * 64, vtg);
  k_attn<<<1536, 256, 0, stream>>>(qkvbuf, vtg, bias, ctx);
  k_gemm_proj<<<dim3(64, 6), 256, 0, stream>>>(ctx, proj_wt, proj_b, out);
}